// Round 1
// baseline (80.791 us; speedup 1.0000x reference)
//
#include <hip/hip_runtime.h>
#include <type_traits>

typedef __attribute__((ext_vector_type(4))) float f32x4;
typedef __attribute__((ext_vector_type(8))) short s16x8;

__device__ __forceinline__ unsigned short f2bf(float f) {
    unsigned int u = __builtin_bit_cast(unsigned int, f);
    u += 0x7fffu + ((u >> 16) & 1u);           // round-to-nearest-even
    return (unsigned short)(u >> 16);
}

// ---------------------------------------------------------------------------
// W [K x N] f32 row-major  ->  Wt [N x K] bf16 row-major
// ---------------------------------------------------------------------------
__global__ void transpose_conv(const float* __restrict__ W,
                               unsigned short* __restrict__ Wt,
                               int K, int N) {
    __shared__ unsigned short tile[32][33];
    const int k0 = blockIdx.x * 32, n0 = blockIdx.y * 32;
    #pragma unroll
    for (int i = threadIdx.y; i < 32; i += 8)
        tile[i][threadIdx.x] = f2bf(W[(size_t)(k0 + i) * N + n0 + threadIdx.x]);
    __syncthreads();
    #pragma unroll
    for (int i = threadIdx.y; i < 32; i += 8)
        Wt[(size_t)(n0 + i) * K + k0 + threadIdx.x] = tile[threadIdx.x][i];
}

// ---------------------------------------------------------------------------
// Staging helpers: tile is ROWS x 64 elements -> LDS bf16, 128 B per row,
// XOR-swizzled 16B chunks: chunk_sw = chunk ^ (row & 7)   (G4 fix)
// ---------------------------------------------------------------------------
template<int ROWS>
__device__ __forceinline__ void stage_f32(const float* __restrict__ src, int ld,
                                          int row0, int k0, int maxRowExcl,
                                          char* lds, int tid) {
    const int r_in = tid >> 4;      // 16 threads per row (float4 each)
    const int c4   = tid & 15;
    #pragma unroll
    for (int p = 0; p < ROWS / 16; ++p) {
        const int row = p * 16 + r_in;
        int gr = row0 + row; if (gr >= maxRowExcl) gr = maxRowExcl - 1;
        const f32x4 v = *reinterpret_cast<const f32x4*>(src + (size_t)gr * ld + k0 + c4 * 4);
        const unsigned int lo = (unsigned)f2bf(v.x) | ((unsigned)f2bf(v.y) << 16);
        const unsigned int hi = (unsigned)f2bf(v.z) | ((unsigned)f2bf(v.w) << 16);
        const int chunk = c4 >> 1;
        const int byte = row * 128 + ((chunk ^ (row & 7)) << 4) + (c4 & 1) * 8;
        *reinterpret_cast<uint2*>(lds + byte) = make_uint2(lo, hi);
    }
}

template<int ROWS>
__device__ __forceinline__ void stage_bf16(const unsigned short* __restrict__ src, int ld,
                                           int row0, int k0, int maxRowExcl,
                                           char* lds, int tid) {
    const int r_in = tid >> 3;      // 8 threads per row (16B each)
    const int ch   = tid & 7;
    #pragma unroll
    for (int p = 0; p < ROWS / 32; ++p) {
        const int row = p * 32 + r_in;
        int gr = row0 + row; if (gr >= maxRowExcl) gr = maxRowExcl - 1;
        const uint4 v = *reinterpret_cast<const uint4*>(src + (size_t)gr * ld + k0 + ch * 8);
        const int byte = row * 128 + ((ch ^ (row & 7)) << 4);
        *reinterpret_cast<uint4*>(lds + byte) = v;
    }
}

// ---------------------------------------------------------------------------
// C[M,N] = A[M,K] @ Bt[N,K]^T   (A: f32 or bf16-bits, Bt: f32 or bf16-bits)
// Block tile: BM=32*MF x BN=32*NF, BK=64, 4 waves in 2x2, 16x16x32 bf16 MFMA
// ---------------------------------------------------------------------------
template<int MF, int NF, typename AT, typename BT, typename CT>
__global__ __launch_bounds__(256) void gemm_bt(const AT* __restrict__ A,
                                               const BT* __restrict__ Bt,
                                               CT* __restrict__ C,
                                               int M, int N, int K,
                                               int lda, int ldb, int ldc) {
    constexpr int BM = 32 * MF, BN = 32 * NF;
    __shared__ __align__(16) char lds[(BM + BN) * 128];
    char* As = lds;
    char* Bs = lds + BM * 128;

    const int tid  = threadIdx.x;
    const int lane = tid & 63;
    const int wid  = tid >> 6;
    const int wm = wid >> 1, wn = wid & 1;
    const int m0 = blockIdx.y * BM, n0 = blockIdx.x * BN;
    const int arow_base = wm * (16 * MF);
    const int brow_base = wn * (16 * NF);
    const int lr = lane & 15;        // fragment row/col within 16
    const int lg = lane >> 4;        // k-group (8 contiguous bf16 each)

    f32x4 acc[MF][NF] = {};

    for (int k0 = 0; k0 < K; k0 += 64) {
        if constexpr (std::is_same<AT, float>::value)
            stage_f32<BM>(A, lda, m0, k0, M, As, tid);
        else
            stage_bf16<BM>(A, lda, m0, k0, M, As, tid);
        if constexpr (std::is_same<BT, float>::value)
            stage_f32<BN>(Bt, ldb, n0, k0, N, Bs, tid);
        else
            stage_bf16<BN>(Bt, ldb, n0, k0, N, Bs, tid);
        __syncthreads();

        #pragma unroll
        for (int kk = 0; kk < 2; ++kk) {
            s16x8 af[MF], bfr[NF];
            const int chunk = kk * 4 + lg;
            #pragma unroll
            for (int f = 0; f < MF; ++f) {
                const int row = arow_base + f * 16 + lr;
                af[f] = *reinterpret_cast<const s16x8*>(As + row * 128 + ((chunk ^ (row & 7)) << 4));
            }
            #pragma unroll
            for (int f = 0; f < NF; ++f) {
                const int row = brow_base + f * 16 + lr;
                bfr[f] = *reinterpret_cast<const s16x8*>(Bs + row * 128 + ((chunk ^ (row & 7)) << 4));
            }
            #pragma unroll
            for (int mi = 0; mi < MF; ++mi)
                #pragma unroll
                for (int ni = 0; ni < NF; ++ni)
                    acc[mi][ni] = __builtin_amdgcn_mfma_f32_16x16x32_bf16(
                        af[mi], bfr[ni], acc[mi][ni], 0, 0, 0);
        }
        __syncthreads();
    }

    // Epilogue: C/D layout col = lane&15, row = (lane>>4)*4 + reg   [m89]
    #pragma unroll
    for (int mi = 0; mi < MF; ++mi) {
        #pragma unroll
        for (int ni = 0; ni < NF; ++ni) {
            const int gcol = n0 + brow_base + ni * 16 + lr;
            if (gcol < N) {
                const int grow0 = m0 + arow_base + mi * 16 + lg * 4;
                #pragma unroll
                for (int r = 0; r < 4; ++r) {
                    const float v = acc[mi][ni][r];
                    if constexpr (std::is_same<CT, float>::value)
                        C[(size_t)(grow0 + r) * ldc + gcol] = v;
                    else
                        C[(size_t)(grow0 + r) * ldc + gcol] = f2bf(v);
                }
            }
        }
    }
}

// ---------------------------------------------------------------------------

extern "C" void kernel_launch(void* const* d_in, const int* in_sizes, int n_in,
                              void* d_out, int out_size, void* d_ws, size_t ws_size,
                              hipStream_t stream) {
    constexpr int B = 512, IMG_D = 1024, WORD_D = 512, NCLS = 20000;

    const float* x = (const float*)d_in[0];     // [512,1024]
    const float* E = (const float*)d_in[1];     // [20000,512]
    const float* W = (const float*)d_in[2];     // [1024,512]
    float* out = (float*)d_out;                 // [512,20000]

    unsigned short* Wt = (unsigned short*)d_ws;                               // [512,1024] bf16
    unsigned short* C1 = (unsigned short*)((char*)d_ws + (size_t)WORD_D * IMG_D * 2); // [512,512] bf16

    // 1) W [1024,512] f32 -> Wt [512,1024] bf16
    transpose_conv<<<dim3(IMG_D / 32, WORD_D / 32), dim3(32, 8), 0, stream>>>(W, Wt, IMG_D, WORD_D);

    // 2) C1[512,512] = x @ W   (bf16 out), 64x64 tiles -> 64 blocks
    gemm_bt<2, 2, float, unsigned short, unsigned short>
        <<<dim3(WORD_D / 64, B / 64), 256, 0, stream>>>(
            x, Wt, C1, B, WORD_D, IMG_D, IMG_D, IMG_D, WORD_D);

    // 3) out[512,20000] = C1 @ E^T  (f32 out), 128x128 tiles -> 157x4 blocks
    gemm_bt<4, 4, unsigned short, float, float>
        <<<dim3((NCLS + 127) / 128, B / 128), 256, 0, stream>>>(
            C1, E, out, B, NCLS, WORD_D, WORD_D, WORD_D, NCLS);
}

// Round 2
// 42.962 us; speedup vs baseline: 1.8805x; 1.8805x over previous
//
#include <hip/hip_runtime.h>
#include <type_traits>

typedef __attribute__((ext_vector_type(4))) float f32x4;
typedef __attribute__((ext_vector_type(8))) short s16x8;

__device__ __forceinline__ unsigned short f2bf(float f) {
    unsigned int u = __builtin_bit_cast(unsigned int, f);
    u += 0x7fffu + ((u >> 16) & 1u);           // round-to-nearest-even
    return (unsigned short)(u >> 16);
}

__device__ __forceinline__ void gload_lds16(const void* g, void* l) {
    __builtin_amdgcn_global_load_lds(
        (const __attribute__((address_space(1))) void*)g,
        (__attribute__((address_space(3))) void*)l, 16, 0, 0);
}

// ---------------------------------------------------------------------------
// LDS tile layout (bf16, 64 k-elems = 128 B per row):
//   byte(row, chunk) = row*128 + ((chunk ^ (row&7)) << 4)
// ---------------------------------------------------------------------------

// Stage ROWS x 64 bf16 tile via global_load_lds: linear LDS dest, source
// pre-swizzled (g_chunk = (l&7) ^ (l>>3), valid since r0 is a multiple of 8).
template<int ROWS>
__device__ __forceinline__ void stage_lds(const unsigned short* __restrict__ src,
                                          int ld, int row0, int k0, int maxRowExcl,
                                          char* lds, int wid, int lane) {
    const int subrow = lane >> 3;            // 0..7
    const int gchunk = (lane & 7) ^ subrow;  // inverse swizzle on source
    #pragma unroll
    for (int p = 0; p < (ROWS + 31) / 32; ++p) {
        const int r0 = (p * 4 + wid) * 8;    // 8 rows / wave-call
        int gr = row0 + r0 + subrow;
        if (gr >= maxRowExcl) gr = maxRowExcl - 1;
        const char* g = (const char*)(src + (size_t)gr * ld + k0) + gchunk * 16;
        gload_lds16(g, lds + r0 * 128);      // wave-uniform base + lane*16
    }
}

// Fallback: f32 source, reg-staged with RNE convert, same swizzled LDS layout.
template<int ROWS>
__device__ __forceinline__ void stage_f32(const float* __restrict__ src, int ld,
                                          int row0, int k0, int maxRowExcl,
                                          char* lds, int tid) {
    const int r_in = tid >> 4;
    const int c4   = tid & 15;
    #pragma unroll
    for (int p = 0; p < ROWS / 16; ++p) {
        const int row = p * 16 + r_in;
        int gr = row0 + row; if (gr >= maxRowExcl) gr = maxRowExcl - 1;
        const f32x4 v = *reinterpret_cast<const f32x4*>(src + (size_t)gr * ld + k0 + c4 * 4);
        const unsigned int lo = (unsigned)f2bf(v.x) | ((unsigned)f2bf(v.y) << 16);
        const unsigned int hi = (unsigned)f2bf(v.z) | ((unsigned)f2bf(v.w) << 16);
        const int chunk = c4 >> 1;
        const int byte = row * 128 + ((chunk ^ (row & 7)) << 4) + (c4 & 1) * 8;
        *reinterpret_cast<uint2*>(lds + byte) = make_uint2(lo, hi);
    }
}

// ---------------------------------------------------------------------------
// C[M,N] = A[M,K] @ B[N,K]^T ; A bf16, B bf16 (gload_lds) or f32 (fallback).
// Tile BM=32*MF x BN=32*NF, BK=64, 4 waves 2x2, 16x16x32 bf16 MFMA.
// ---------------------------------------------------------------------------
template<int MF, int NF, bool BBF, typename CT>
__device__ __forceinline__ void gemm_body(const unsigned short* __restrict__ A,
                                          const void* __restrict__ Bv,
                                          CT* __restrict__ C,
                                          int M, int N, int K,
                                          int lda, int ldb, int ldc,
                                          int bid, int nwg, char* lds) {
    constexpr int BM = 32 * MF, BN = 32 * NF;
    char* As = lds;
    char* Bs = lds + BM * 128;

    // bijective XCD swizzle (m204) — consecutive wgids share the B-panel
    {
        const int q = nwg >> 3, r = nwg & 7;
        const int xcd = bid & 7, idx = bid >> 3;
        bid = (xcd < r ? xcd * (q + 1) : r * (q + 1) + (xcd - r) * q) + idx;
    }
    const int nbM = M / BM;
    const int m0 = (bid % nbM) * BM;
    const int n0 = (bid / nbM) * BN;

    const int tid  = threadIdx.x;
    const int lane = tid & 63;
    const int wid  = tid >> 6;
    const int wm = wid >> 1, wn = wid & 1;
    const int arow_base = wm * (16 * MF);
    const int brow_base = wn * (16 * NF);
    const int lr = lane & 15;
    const int lg = lane >> 4;

    f32x4 acc[MF][NF] = {};

    for (int k0 = 0; k0 < K; k0 += 64) {
        stage_lds<BM>(A, lda, m0, k0, M, As, wid, lane);
        if constexpr (BBF)
            stage_lds<BN>((const unsigned short*)Bv, ldb, n0, k0, N, Bs, wid, lane);
        else
            stage_f32<BN>((const float*)Bv, ldb, n0, k0, N, Bs, tid);
        __syncthreads();

        #pragma unroll
        for (int kk = 0; kk < 2; ++kk) {
            s16x8 af[MF], bfr[NF];
            const int chunk = kk * 4 + lg;
            #pragma unroll
            for (int f = 0; f < MF; ++f) {
                const int row = arow_base + f * 16 + lr;
                af[f] = *reinterpret_cast<const s16x8*>(As + row * 128 + ((chunk ^ (row & 7)) << 4));
            }
            #pragma unroll
            for (int f = 0; f < NF; ++f) {
                const int row = brow_base + f * 16 + lr;
                bfr[f] = *reinterpret_cast<const s16x8*>(Bs + row * 128 + ((chunk ^ (row & 7)) << 4));
            }
            #pragma unroll
            for (int mi = 0; mi < MF; ++mi)
                #pragma unroll
                for (int ni = 0; ni < NF; ++ni)
                    acc[mi][ni] = __builtin_amdgcn_mfma_f32_16x16x32_bf16(
                        af[mi], bfr[ni], acc[mi][ni], 0, 0, 0);
        }
        __syncthreads();
    }

    // Epilogue: C/D layout col = lane&15, row = (lane>>4)*4 + reg   [m89]
    #pragma unroll
    for (int mi = 0; mi < MF; ++mi) {
        #pragma unroll
        for (int ni = 0; ni < NF; ++ni) {
            const int gcol = n0 + brow_base + ni * 16 + lr;
            if (gcol < N) {
                const int grow0 = m0 + arow_base + mi * 16 + lg * 4;
                #pragma unroll
                for (int r = 0; r < 4; ++r) {
                    const float v = acc[mi][ni][r];
                    if constexpr (std::is_same<CT, float>::value)
                        C[(size_t)(grow0 + r) * ldc + gcol] = v;
                    else
                        C[(size_t)(grow0 + r) * ldc + gcol] = f2bf(v);
                }
            }
        }
    }
}

// ---------------------------------------------------------------------------
// Launch 1: W -> Wt (bf16 transpose) + x -> xb (bf16). 768 blocks.
// ---------------------------------------------------------------------------
__global__ __launch_bounds__(256) void prep_wx(const float* __restrict__ W,
                                               const float* __restrict__ x,
                                               unsigned short* __restrict__ Wt,
                                               unsigned short* __restrict__ xb) {
    const int bid = blockIdx.x, t = threadIdx.x;
    if (bid < 512) {
        __shared__ unsigned short tile[32][33];
        const int k0 = (bid & 31) * 32, n0 = (bid >> 5) * 32;
        const int c = t & 31, y = t >> 5;
        #pragma unroll
        for (int j = 0; j < 4; ++j)
            tile[y + j * 8][c] = f2bf(W[(size_t)(k0 + y + j * 8) * 512 + n0 + c]);
        __syncthreads();
        #pragma unroll
        for (int j = 0; j < 4; ++j)
            Wt[(size_t)(n0 + y + j * 8) * 1024 + k0 + c] = tile[c][y + j * 8];
    } else {
        const size_t base = (size_t)(bid - 512) * 2048 + (size_t)t * 8;
        const f32x4 v0 = *reinterpret_cast<const f32x4*>(x + base);
        const f32x4 v1 = *reinterpret_cast<const f32x4*>(x + base + 4);
        uint4 o;
        o.x = (unsigned)f2bf(v0.x) | ((unsigned)f2bf(v0.y) << 16);
        o.y = (unsigned)f2bf(v0.z) | ((unsigned)f2bf(v0.w) << 16);
        o.z = (unsigned)f2bf(v1.x) | ((unsigned)f2bf(v1.y) << 16);
        o.w = (unsigned)f2bf(v1.z) | ((unsigned)f2bf(v1.w) << 16);
        *reinterpret_cast<uint4*>(xb + base) = o;
    }
}

// ---------------------------------------------------------------------------
// Launch 2: blocks 0..127 = GEMM1 (C1 = xb @ Wt^T, bf16 out, tile 32x64);
//           blocks 128..  = E f32 -> Eb bf16 convert (streams alongside).
// ---------------------------------------------------------------------------
__global__ __launch_bounds__(256) void gemm1_fused(const unsigned short* __restrict__ xb,
                                                   const unsigned short* __restrict__ Wt,
                                                   unsigned short* __restrict__ C1,
                                                   const float* __restrict__ E,
                                                   unsigned short* __restrict__ Eb) {
    __shared__ __align__(16) char lds[(32 + 64) * 128];
    const int bid = blockIdx.x;
    if (bid < 128) {
        gemm_body<1, 2, true, unsigned short>(xb, Wt, C1, 512, 512, 1024,
                                              1024, 1024, 512, bid, 128, lds);
    } else {
        const size_t base = (size_t)(bid - 128) * 2048 + (size_t)threadIdx.x * 8;
        const f32x4 v0 = *reinterpret_cast<const f32x4*>(E + base);
        const f32x4 v1 = *reinterpret_cast<const f32x4*>(E + base + 4);
        uint4 o;
        o.x = (unsigned)f2bf(v0.x) | ((unsigned)f2bf(v0.y) << 16);
        o.y = (unsigned)f2bf(v0.z) | ((unsigned)f2bf(v0.w) << 16);
        o.z = (unsigned)f2bf(v1.x) | ((unsigned)f2bf(v1.y) << 16);
        o.w = (unsigned)f2bf(v1.z) | ((unsigned)f2bf(v1.w) << 16);
        *reinterpret_cast<uint4*>(Eb + base) = o;
    }
}

// ---------------------------------------------------------------------------
// Launch 3: out = C1 @ E^T  (f32 out), tile 128x128 -> 628 blocks
// ---------------------------------------------------------------------------
template<bool BBF>
__global__ __launch_bounds__(256) void gemm2k(const unsigned short* __restrict__ C1,
                                              const void* __restrict__ Bv,
                                              float* __restrict__ out) {
    __shared__ __align__(16) char lds[(128 + 128) * 128];
    gemm_body<4, 4, BBF, float>(C1, Bv, out, 512, 20000, 512,
                                512, 512, 20000, (int)blockIdx.x, (int)gridDim.x, lds);
}

// ---------------------------------------------------------------------------

extern "C" void kernel_launch(void* const* d_in, const int* in_sizes, int n_in,
                              void* d_out, int out_size, void* d_ws, size_t ws_size,
                              hipStream_t stream) {
    const float* x = (const float*)d_in[0];     // [512,1024]
    const float* E = (const float*)d_in[1];     // [20000,512]
    const float* W = (const float*)d_in[2];     // [1024,512]
    float* out = (float*)d_out;                 // [512,20000]

    char* ws = (char*)d_ws;
    unsigned short* C1 = (unsigned short*)ws;                     // 512 KiB
    unsigned short* xb = (unsigned short*)(ws + 524288);          // 1 MiB
    unsigned short* Wt = (unsigned short*)(ws + 1572864);         // 1 MiB
    unsigned short* Eb = (unsigned short*)(ws + 2621440);         // 20.48 MB
    const bool EBF = ws_size >= (size_t)23101440;                 // Eb fits?

    // 1) Wt + xb
    prep_wx<<<768, 256, 0, stream>>>(W, x, Wt, xb);

    // 2) GEMM1 (128 blocks) fused with E->bf16 convert (5000 blocks)
    gemm1_fused<<<EBF ? 5128 : 128, 256, 0, stream>>>(xb, Wt, C1, E, Eb);

    // 3) GEMM2: 157 N-tiles x 4 M-tiles
    if (EBF)
        gemm2k<true><<<157 * 4, 256, 0, stream>>>(C1, (const void*)Eb, out);
    else
        gemm2k<false><<<157 * 4, 256, 0, stream>>>(C1, (const void*)E, out);
}